// Round 1
// baseline (77.063 us; speedup 1.0000x reference)
//
#include <hip/hip_runtime.h>
#include <cmath>

#define SEQ 4096
#define NB 16
#define LIMIT 30
#define NT 1024

// One block per batch row. Thread t owns elements [4t, 4t+4).
__global__ __launch_bounds__(NT, 1) void ph_kernel(
    const float* __restrict__ sl_g, const float* __restrict__ el_g,
    float* __restrict__ out) {
  const int b = blockIdx.x;
  const int tid = threadIdx.x;
  const int lane = tid & 63;
  const int wv = tid >> 6;  // 16 waves

  __shared__ float s_sp[SEQ];
  __shared__ float s_ep[SEQ];
  __shared__ float rmax_s[16], rmax_e[16], rsum_s[16], rsum_e[16];
  __shared__ float rav[16], rbv[16];
  __shared__ int   rai[16], rbi[16];
  __shared__ float f_max_s, f_max_e, f_sum_s, f_sum_e;

  const int i0 = tid << 2;
  float4 sv = *(const float4*)(sl_g + b * SEQ + i0);
  float4 ev = *(const float4*)(el_g + b * SEQ + i0);

  // ---------- block max (both logit rows in one pass) ----------
  float ms = fmaxf(fmaxf(sv.x, sv.y), fmaxf(sv.z, sv.w));
  float me = fmaxf(fmaxf(ev.x, ev.y), fmaxf(ev.z, ev.w));
#pragma unroll
  for (int off = 32; off; off >>= 1) {
    ms = fmaxf(ms, __shfl_down(ms, off, 64));
    me = fmaxf(me, __shfl_down(me, off, 64));
  }
  if (lane == 0) { rmax_s[wv] = ms; rmax_e[wv] = me; }
  __syncthreads();
  if (tid < 16) {
    float a = rmax_s[tid], c = rmax_e[tid];
#pragma unroll
    for (int off = 8; off; off >>= 1) {
      a = fmaxf(a, __shfl_down(a, off, 16));
      c = fmaxf(c, __shfl_down(c, off, 16));
    }
    if (tid == 0) { f_max_s = a; f_max_e = c; }
  }
  __syncthreads();
  const float max_s = f_max_s, max_e = f_max_e;

  // ---------- exp + block sum ----------
  float es0 = expf(sv.x - max_s), es1 = expf(sv.y - max_s),
        es2 = expf(sv.z - max_s), es3 = expf(sv.w - max_s);
  float ee0 = expf(ev.x - max_e), ee1 = expf(ev.y - max_e),
        ee2 = expf(ev.z - max_e), ee3 = expf(ev.w - max_e);
  float ss = (es0 + es1) + (es2 + es3);
  float se = (ee0 + ee1) + (ee2 + ee3);
#pragma unroll
  for (int off = 32; off; off >>= 1) {
    ss += __shfl_down(ss, off, 64);
    se += __shfl_down(se, off, 64);
  }
  if (lane == 0) { rsum_s[wv] = ss; rsum_e[wv] = se; }
  __syncthreads();
  if (tid < 16) {
    float a = rsum_s[tid], c = rsum_e[tid];
#pragma unroll
    for (int off = 8; off; off >>= 1) {
      a += __shfl_down(a, off, 16);
      c += __shfl_down(c, off, 16);
    }
    if (tid == 0) { f_sum_s = a; f_sum_e = c; }
  }
  __syncthreads();
  const float inv_s = 1.0f / f_sum_s;
  const float inv_e = 1.0f / f_sum_e;

  // ---------- normalized probs -> global (float4) + LDS ----------
  float4 ps = make_float4(es0 * inv_s, es1 * inv_s, es2 * inv_s, es3 * inv_s);
  float4 pe = make_float4(ee0 * inv_e, ee1 * inv_e, ee2 * inv_e, ee3 * inv_e);
  *(float4*)(out + b * SEQ + i0) = ps;
  *(float4*)(out + NB * SEQ + b * SEQ + i0) = pe;
  s_sp[i0] = ps.x; s_sp[i0 + 1] = ps.y; s_sp[i0 + 2] = ps.z; s_sp[i0 + 3] = ps.w;
  s_ep[i0] = pe.x; s_ep[i0 + 1] = pe.y; s_ep[i0 + 2] = pe.z; s_ep[i0 + 3] = pe.w;
  __syncthreads();

  // ---------- banded-window max + argmax ----------
  // start_ptr: argmax_i sp[i] * max(ep[i..i+30]);  end_ptr: argmax_j ep[j] * max(sp[j-30..j])
  float bsv = -1.0f, bev = -1.0f;
  int bsi = 0, bei = 0;
#pragma unroll
  for (int k = 0; k < 4; ++k) {
    const int i = i0 + k;
    const int hi = min(i + LIMIT, SEQ - 1);
    float wm = 0.0f;
    for (int j = i; j <= hi; ++j) wm = fmaxf(wm, s_ep[j]);
    const float v1 = s_sp[i] * wm;
    if (v1 > bsv) { bsv = v1; bsi = i; }  // ascending i: '>' keeps first occurrence
    const int lo = max(i - LIMIT, 0);
    float wm2 = 0.0f;
    for (int j = lo; j <= i; ++j) wm2 = fmaxf(wm2, s_sp[j]);
    const float v2 = s_ep[i] * wm2;
    if (v2 > bev) { bev = v2; bei = i; }
  }
#pragma unroll
  for (int off = 32; off; off >>= 1) {
    float ov = __shfl_down(bsv, off, 64);
    int oi = __shfl_down(bsi, off, 64);
    if (ov > bsv || (ov == bsv && oi < bsi)) { bsv = ov; bsi = oi; }
    float ov2 = __shfl_down(bev, off, 64);
    int oi2 = __shfl_down(bei, off, 64);
    if (ov2 > bev || (ov2 == bev && oi2 < bei)) { bev = ov2; bei = oi2; }
  }
  if (lane == 0) { rav[wv] = bsv; rai[wv] = bsi; rbv[wv] = bev; rbi[wv] = bei; }
  __syncthreads();
  if (tid < 16) {
    float av = rav[tid]; int ai = rai[tid];
    float bv = rbv[tid]; int bi = rbi[tid];
#pragma unroll
    for (int off = 8; off; off >>= 1) {
      float ov = __shfl_down(av, off, 16);
      int oi = __shfl_down(ai, off, 16);
      if (ov > av || (ov == av && oi < ai)) { av = ov; ai = oi; }
      float ov2 = __shfl_down(bv, off, 16);
      int oi2 = __shfl_down(bi, off, 16);
      if (ov2 > bv || (ov2 == bv && oi2 < bi)) { bv = ov2; bi = oi2; }
    }
    if (tid == 0) {
      out[2 * NB * SEQ + b] = (float)ai;        // start_pointer
      out[2 * NB * SEQ + NB + b] = (float)bi;   // end_pointer
    }
  }
}

extern "C" void kernel_launch(void* const* d_in, const int* in_sizes, int n_in,
                              void* d_out, int out_size, void* d_ws, size_t ws_size,
                              hipStream_t stream) {
  const float* start_logits = (const float*)d_in[0];
  const float* end_logits = (const float*)d_in[1];
  float* out = (float*)d_out;
  ph_kernel<<<NB, NT, 0, stream>>>(start_logits, end_logits, out);
}

// Round 2
// 59.394 us; speedup vs baseline: 1.2975x; 1.2975x over previous
//
#include <hip/hip_runtime.h>
#include <cmath>

#define SEQ 4096
#define NB 16
#define LIMIT 30
#define NT 1024
#define PAD 34   // >= LIMIT+4, chosen so padded bases stay 16B-aligned

// One block per batch row. Thread t owns elements [4t, 4t+4).
// LDS layouts:
//   s_ep[i]        = end_prob[i],   i in [0,SEQ); s_ep[SEQ..SEQ+PAD) = 0
//   s_spp[PAD + i] = start_prob[i]; s_spp[0..PAD) = 0
// Window maxes then need no bounds clamps (probs > 0, zero pads never win).
__global__ __launch_bounds__(NT, 1) void ph_kernel(
    const float* __restrict__ sl_g, const float* __restrict__ el_g,
    float* __restrict__ out) {
  const int b = blockIdx.x;
  const int tid = threadIdx.x;
  const int lane = tid & 63;
  const int wv = tid >> 6;  // 16 waves

  __shared__ float s_ep[SEQ + PAD];
  __shared__ float s_spp[SEQ + PAD];
  __shared__ float rmax_s[16], rmax_e[16], rsum_s[16], rsum_e[16];
  __shared__ float rav[16], rbv[16];
  __shared__ int   rai[16], rbi[16];
  __shared__ float f_max_s, f_max_e, f_sum_s, f_sum_e;

  // zero the pads once, up front (covered by the syncthreads below)
  if (tid < PAD) {
    s_ep[SEQ + tid] = 0.0f;
    s_spp[tid] = 0.0f;
  }

  const int i0 = tid << 2;
  float4 sv = *(const float4*)(sl_g + b * SEQ + i0);
  float4 ev = *(const float4*)(el_g + b * SEQ + i0);

  // ---------- block max (both logit rows in one pass) ----------
  float ms = fmaxf(fmaxf(sv.x, sv.y), fmaxf(sv.z, sv.w));
  float me = fmaxf(fmaxf(ev.x, ev.y), fmaxf(ev.z, ev.w));
#pragma unroll
  for (int off = 32; off; off >>= 1) {
    ms = fmaxf(ms, __shfl_down(ms, off, 64));
    me = fmaxf(me, __shfl_down(me, off, 64));
  }
  if (lane == 0) { rmax_s[wv] = ms; rmax_e[wv] = me; }
  __syncthreads();
  if (tid < 16) {
    float a = rmax_s[tid], c = rmax_e[tid];
#pragma unroll
    for (int off = 8; off; off >>= 1) {
      a = fmaxf(a, __shfl_down(a, off, 16));
      c = fmaxf(c, __shfl_down(c, off, 16));
    }
    if (tid == 0) { f_max_s = a; f_max_e = c; }
  }
  __syncthreads();
  const float max_s = f_max_s, max_e = f_max_e;

  // ---------- exp + block sum ----------
  float es0 = expf(sv.x - max_s), es1 = expf(sv.y - max_s),
        es2 = expf(sv.z - max_s), es3 = expf(sv.w - max_s);
  float ee0 = expf(ev.x - max_e), ee1 = expf(ev.y - max_e),
        ee2 = expf(ev.z - max_e), ee3 = expf(ev.w - max_e);
  float ss = (es0 + es1) + (es2 + es3);
  float se = (ee0 + ee1) + (ee2 + ee3);
#pragma unroll
  for (int off = 32; off; off >>= 1) {
    ss += __shfl_down(ss, off, 64);
    se += __shfl_down(se, off, 64);
  }
  if (lane == 0) { rsum_s[wv] = ss; rsum_e[wv] = se; }
  __syncthreads();
  if (tid < 16) {
    float a = rsum_s[tid], c = rsum_e[tid];
#pragma unroll
    for (int off = 8; off; off >>= 1) {
      a += __shfl_down(a, off, 16);
      c += __shfl_down(c, off, 16);
    }
    if (tid == 0) { f_sum_s = a; f_sum_e = c; }
  }
  __syncthreads();
  const float inv_s = 1.0f / f_sum_s;
  const float inv_e = 1.0f / f_sum_e;

  // ---------- normalized probs -> global (float4) + LDS ----------
  float4 ps = make_float4(es0 * inv_s, es1 * inv_s, es2 * inv_s, es3 * inv_s);
  float4 pe = make_float4(ee0 * inv_e, ee1 * inv_e, ee2 * inv_e, ee3 * inv_e);
  *(float4*)(out + b * SEQ + i0) = ps;
  *(float4*)(out + NB * SEQ + b * SEQ + i0) = pe;
  s_spp[PAD + i0] = ps.x; s_spp[PAD + i0 + 1] = ps.y;
  s_spp[PAD + i0 + 2] = ps.z; s_spp[PAD + i0 + 3] = ps.w;
  s_ep[i0] = pe.x; s_ep[i0 + 1] = pe.y; s_ep[i0 + 2] = pe.z; s_ep[i0 + 3] = pe.w;
  __syncthreads();

  // ---------- banded-window max + argmax (fully unrolled, no clamps) ----------
  // start side: need ep window [i0+k .. i0+k+30] for k=0..3.
  //   v[j] = s_ep[i0 + j], j = 0..33. common = max(v[3..30]).
  //   w(k) built from common + 3 boundary elems each.
  float v0 = s_ep[i0], v1 = s_ep[i0 + 1], v2 = s_ep[i0 + 2];
  float common = s_ep[i0 + 3];
#pragma unroll
  for (int j = 4; j <= 30; ++j) common = fmaxf(common, s_ep[i0 + j]);
  float v31 = s_ep[i0 + 31], v32 = s_ep[i0 + 32], v33 = s_ep[i0 + 33];
  float w0 = fmaxf(common, fmaxf(v0, fmaxf(v1, v2)));
  float w1 = fmaxf(common, fmaxf(v1, fmaxf(v2, v31)));
  float w2 = fmaxf(common, fmaxf(v2, fmaxf(v31, v32)));
  float w3 = fmaxf(common, fmaxf(v31, fmaxf(v32, v33)));

  // end side: need sp window [i0+k-30 .. i0+k] for k=0..3.
  //   u[j] = s_spp[4 + i0 + j] = sp[i0 - 30 + j], j = 0..33. common2 = max(u[3..30]).
  const int ub = 4 + i0;
  float u0 = s_spp[ub], u1 = s_spp[ub + 1], u2 = s_spp[ub + 2];
  float common2 = s_spp[ub + 3];
#pragma unroll
  for (int j = 4; j <= 30; ++j) common2 = fmaxf(common2, s_spp[ub + j]);
  float u31 = s_spp[ub + 31], u32 = s_spp[ub + 32], u33 = s_spp[ub + 33];
  float x0 = fmaxf(common2, fmaxf(u0, fmaxf(u1, u2)));
  float x1 = fmaxf(common2, fmaxf(u1, fmaxf(u2, u31)));
  float x2 = fmaxf(common2, fmaxf(u2, fmaxf(u31, u32)));
  float x3 = fmaxf(common2, fmaxf(u31, fmaxf(u32, u33)));

  // scores
  float sc0 = ps.x * w0, sc1 = ps.y * w1, sc2 = ps.z * w2, sc3 = ps.w * w3;
  float tc0 = pe.x * x0, tc1 = pe.y * x1, tc2 = pe.z * x2, tc3 = pe.w * x3;

  // per-thread argmax (ascending index, '>' keeps first occurrence)
  float bsv = sc0; int bsi = i0;
  if (sc1 > bsv) { bsv = sc1; bsi = i0 + 1; }
  if (sc2 > bsv) { bsv = sc2; bsi = i0 + 2; }
  if (sc3 > bsv) { bsv = sc3; bsi = i0 + 3; }
  float bev = tc0; int bei = i0;
  if (tc1 > bev) { bev = tc1; bei = i0 + 1; }
  if (tc2 > bev) { bev = tc2; bei = i0 + 2; }
  if (tc3 > bev) { bev = tc3; bei = i0 + 3; }

#pragma unroll
  for (int off = 32; off; off >>= 1) {
    float ov = __shfl_down(bsv, off, 64);
    int oi = __shfl_down(bsi, off, 64);
    if (ov > bsv || (ov == bsv && oi < bsi)) { bsv = ov; bsi = oi; }
    float ov2 = __shfl_down(bev, off, 64);
    int oi2 = __shfl_down(bei, off, 64);
    if (ov2 > bev || (ov2 == bev && oi2 < bei)) { bev = ov2; bei = oi2; }
  }
  if (lane == 0) { rav[wv] = bsv; rai[wv] = bsi; rbv[wv] = bev; rbi[wv] = bei; }
  __syncthreads();
  if (tid < 16) {
    float av = rav[tid]; int ai = rai[tid];
    float bv = rbv[tid]; int bi = rbi[tid];
#pragma unroll
    for (int off = 8; off; off >>= 1) {
      float ov = __shfl_down(av, off, 16);
      int oi = __shfl_down(ai, off, 16);
      if (ov > av || (ov == av && oi < ai)) { av = ov; ai = oi; }
      float ov2 = __shfl_down(bv, off, 16);
      int oi2 = __shfl_down(bi, off, 16);
      if (ov2 > bv || (ov2 == bv && oi2 < bi)) { bv = ov2; bi = oi2; }
    }
    if (tid == 0) {
      out[2 * NB * SEQ + b] = (float)ai;        // start_pointer
      out[2 * NB * SEQ + NB + b] = (float)bi;   // end_pointer
    }
  }
}

extern "C" void kernel_launch(void* const* d_in, const int* in_sizes, int n_in,
                              void* d_out, int out_size, void* d_ws, size_t ws_size,
                              hipStream_t stream) {
  const float* start_logits = (const float*)d_in[0];
  const float* end_logits = (const float*)d_in[1];
  float* out = (float*)d_out;
  ph_kernel<<<NB, NT, 0, stream>>>(start_logits, end_logits, out);
}